// Round 1
// baseline (1218.411 us; speedup 1.0000x reference)
//
#include <hip/hip_runtime.h>
#include <hip/hip_bf16.h>

// DeepSeek V3 MLA attention forward, MI355X (gfx950).
// Constants from reference: B=2, S=2048, D=2048, H=16, NOPE=128, ROPE=64,
// VDIM=128, QKD=192, EPS=1e-6, SCALING=192^-0.5.

typedef __bf16 bf16x8 __attribute__((ext_vector_type(8)));
typedef float floatx4 __attribute__((ext_vector_type(4)));
#define BF16 __hip_bfloat16

static __device__ __forceinline__ BF16 f2b(float x) { return __float2bfloat16(x); }

// ---------------------------------------------------------------- cast f32->bf16
__global__ void cast_bf16_k(const float* __restrict__ x, BF16* __restrict__ y, long n) {
  long i = ((long)blockIdx.x * 256 + threadIdx.x) * 4;
  if (i + 3 < n) {
    float4 v = *(const float4*)(x + i);
    y[i+0] = f2b(v.x); y[i+1] = f2b(v.y); y[i+2] = f2b(v.z); y[i+3] = f2b(v.w);
  }
}

// ---------------------------------------------------------------- NT GEMM
// C[M][N] = A[M][K] * B[N][K]^T, bf16 in, fp32 accumulate.
// 256 threads = 4 waves (2x2), 128x128 block tile, 64x64 per wave (4x4 mfma tiles).
template<bool OUT_BF16>
__global__ __launch_bounds__(256) void gemm_nt(const BF16* __restrict__ A, const BF16* __restrict__ B,
                                               void* __restrict__ C, int M, int N, int K) {
  int tid = threadIdx.x;
  int wave = tid >> 6, lane = tid & 63;
  int wr = wave >> 1, wc = wave & 1;
  int lr = lane & 15, quad = lane >> 4;
  long m0 = (long)blockIdx.y * 128 + wr * 64;
  long n0 = (long)blockIdx.x * 128 + wc * 64;
  floatx4 acc[4][4] = {};
  for (int k0 = 0; k0 < K; k0 += 32) {
    bf16x8 a[4], b[4];
#pragma unroll
    for (int i = 0; i < 4; i++) {
      long r = m0 + i*16 + lr; if (r >= M) r = M - 1;
      a[i] = *(const bf16x8*)(A + r*(long)K + k0 + quad*8);
    }
#pragma unroll
    for (int j = 0; j < 4; j++) {
      long c = n0 + j*16 + lr; if (c >= N) c = N - 1;
      b[j] = *(const bf16x8*)(B + c*(long)K + k0 + quad*8);
    }
#pragma unroll
    for (int i = 0; i < 4; i++)
#pragma unroll
      for (int j = 0; j < 4; j++)
        acc[i][j] = __builtin_amdgcn_mfma_f32_16x16x32_bf16(a[i], b[j], acc[i][j], 0, 0, 0);
  }
#pragma unroll
  for (int i = 0; i < 4; i++)
#pragma unroll
    for (int j = 0; j < 4; j++) {
      long col = n0 + j*16 + lr;
      if (col < N) {
#pragma unroll
        for (int r = 0; r < 4; r++) {
          long row = m0 + i*16 + quad*4 + r;
          if (row < M) {
            if (OUT_BF16) ((BF16*)C)[row*(long)N + col] = f2b(acc[i][j][r]);
            else          ((float*)C)[row*(long)N + col] = acc[i][j][r];
          }
        }
      }
    }
}

// ---------------------------------------------------------------- RMSNorm (row-wise), fp32 in, bf16 out
template<int D>
__global__ __launch_bounds__(256) void rmsnorm_k(const float* __restrict__ x, const float* __restrict__ w,
                                                 BF16* __restrict__ y, int ld_in, int ld_out) {
  long row = blockIdx.x;
  const float* xr = x + row * (long)ld_in;
  float ss = 0.f;
  for (int i = threadIdx.x * 4; i < D; i += 1024) {
    float4 v = *(const float4*)(xr + i);
    ss += v.x*v.x + v.y*v.y + v.z*v.z + v.w*v.w;
  }
#pragma unroll
  for (int off = 32; off > 0; off >>= 1) ss += __shfl_down(ss, off);
  __shared__ float red[4];
  if ((threadIdx.x & 63) == 0) red[threadIdx.x >> 6] = ss;
  __syncthreads();
  float tot = red[0] + red[1] + red[2] + red[3];
  float rs = rsqrtf(tot / (float)D + 1e-6f);
  BF16* yr = y + row * (long)ld_out;
  for (int i = threadIdx.x * 4; i < D; i += 1024) {
    float4 v = *(const float4*)(xr + i);
    yr[i+0] = f2b(v.x * w[i+0] * rs);
    yr[i+1] = f2b(v.y * w[i+1] * rs);
    yr[i+2] = f2b(v.z * w[i+2] * rs);
    yr[i+3] = f2b(v.w * w[i+3] * rs);
  }
}

// ---------------------------------------------------------------- RoPE on q, gather to (B,H,S,192) bf16
__global__ void prep_q_k(const float* __restrict__ q, const float* __restrict__ cosb,
                         const float* __restrict__ sinb, BF16* __restrict__ Qt) {
  // grid (S, H, B), block 192
  int s = blockIdx.x, h = blockIdx.y, b = blockIdx.z, d = threadIdx.x;
  long row = (long)b * 2048 + s;
  const float* qr = q + row * 3072 + h * 192;
  float val;
  if (d < 128) {
    val = qr[d];
  } else {
    int i = d - 128;
    float x = qr[d];
    float rot = (i < 32) ? -qr[128 + i + 32] : qr[128 + i - 32];
    val = x * cosb[row*64 + i] + rot * sinb[row*64 + i];
  }
  Qt[(((long)b*16 + h)*2048 + s)*192 + d] = f2b(val);
}

// ---------------------------------------------------------------- RoPE on k_rot (per b,s), bf16 out
__global__ void prep_krot_k(const float* __restrict__ ckv, const float* __restrict__ cosb,
                            const float* __restrict__ sinb, BF16* __restrict__ Krot) {
  // grid 4096, block 64
  long row = blockIdx.x; int i = threadIdx.x;
  const float* kr = ckv + row * 576 + 512;
  float x = kr[i];
  float rot = (i < 32) ? -kr[i + 32] : kr[i - 32];
  Krot[row*64 + i] = f2b(x * cosb[row*64 + i] + rot * sinb[row*64 + i]);
}

// ---------------------------------------------------------------- gather kv -> K (B,H,S,192), V (B,H,S,128)
__global__ void rearrange_kv_k(const BF16* __restrict__ kv, const BF16* __restrict__ Krot,
                               BF16* __restrict__ Kt, BF16* __restrict__ Vt) {
  // grid (S, H, B), block 64
  int s = blockIdx.x, h = blockIdx.y, b = blockIdx.z, t = threadIdx.x;
  long row = (long)b * 2048 + s;
  const BF16* src = kv + row * 4096 + h * 256;
  long kbase = (((long)b*16 + h)*2048 + s) * 192;
  long vbase = (((long)b*16 + h)*2048 + s) * 128;
  for (int d = t; d < 128; d += 64) {
    Kt[kbase + d] = src[d];
    Vt[vbase + d] = src[128 + d];
  }
  Kt[kbase + 128 + t] = Krot[row*64 + t];
}

// ---------------------------------------------------------------- causal flash attention
// grid (S/64, H, B); 256 threads = 4 waves; wave w owns q rows [q0+16w, q0+16w+16).
__global__ __launch_bounds__(256) void flash_k(const BF16* __restrict__ Qt, const BF16* __restrict__ Kt,
                                               const BF16* __restrict__ Vt, BF16* __restrict__ O) {
  __shared__ __align__(16) BF16 Ks[64*192];   // K tile [kpos][d]
  __shared__ __align__(16) BF16 Vs[128*64];   // V tile transposed [vd][kpos]
  __shared__ __align__(16) BF16 Ps[4][16*64]; // per-wave P [q][kpos]
  int tid = threadIdx.x, wave = tid >> 6, lane = tid & 63;
  int lr = lane & 15, quad = lane >> 4;
  int b = blockIdx.z, h = blockIdx.y;
  int q0 = blockIdx.x * 64;
  const BF16* Qb = Qt + ((long)(b*16 + h) * 2048) * 192;
  const BF16* Kb = Kt + ((long)(b*16 + h) * 2048) * 192;
  const BF16* Vb = Vt + ((long)(b*16 + h) * 2048) * 128;
  bf16x8 qf[6];
  {
    const BF16* qp = Qb + (long)(q0 + wave*16 + lr) * 192 + quad*8;
#pragma unroll
    for (int f = 0; f < 6; f++) qf[f] = *(const bf16x8*)(qp + f*32);
  }
  const float NEG_INF = -__builtin_inff();
  float m_i[4], l_i[4];
#pragma unroll
  for (int r = 0; r < 4; r++) { m_i[r] = NEG_INF; l_i[r] = 0.f; }
  floatx4 o_acc[8] = {};
  const float scale = 0.07216878364870322f; // 192^-0.5
  int nk = blockIdx.x + 1;
  for (int kt = 0; kt < nk; kt++) {
    int k0 = kt * 64;
    __syncthreads(); // protect prev-iter LDS reads before restaging
    for (int c = tid; c < 1536; c += 256) {  // 64x192 K tile, 16B chunks
      int row = c / 24, col = (c % 24) * 8;
      *(bf16x8*)(Ks + row*192 + col) = *(const bf16x8*)(Kb + (long)(k0+row)*192 + col);
    }
    for (int e = tid; e < 1024; e += 256) {  // 64x128 V tile -> transposed
      int kpos = e >> 4, vd0 = (e & 15) * 8;
      bf16x8 v = *(const bf16x8*)(Vb + (long)(k0+kpos)*128 + vd0);
#pragma unroll
      for (int j = 0; j < 8; j++) Vs[(vd0+j)*64 + kpos] = ((BF16*)&v)[j];
    }
    __syncthreads();
    // scores: 16 q rows x 64 k cols = 4 C tiles
    floatx4 st[4];
#pragma unroll
    for (int t = 0; t < 4; t++) {
      floatx4 c = {};
#pragma unroll
      for (int f = 0; f < 6; f++) {
        bf16x8 kf = *(const bf16x8*)(Ks + (t*16+lr)*192 + f*32 + quad*8);
        c = __builtin_amdgcn_mfma_f32_16x16x32_bf16(qf[f], kf, c, 0, 0, 0);
      }
      st[t] = c;
    }
    int rowbase = q0 + wave*16 + quad*4;
    float mt[4];
#pragma unroll
    for (int r = 0; r < 4; r++) mt[r] = NEG_INF;
#pragma unroll
    for (int t = 0; t < 4; t++) {
      int col = k0 + t*16 + lr;
#pragma unroll
      for (int r = 0; r < 4; r++) {
        float s = st[t][r] * scale;
        if (col > rowbase + r) s = NEG_INF;
        st[t][r] = s;
        mt[r] = fmaxf(mt[r], s);
      }
    }
#pragma unroll
    for (int off = 1; off < 16; off <<= 1)
#pragma unroll
      for (int r = 0; r < 4; r++) mt[r] = fmaxf(mt[r], __shfl_xor(mt[r], off));
    float alpha[4], rsum[4];
#pragma unroll
    for (int r = 0; r < 4; r++) {
      float mn = fmaxf(m_i[r], mt[r]);
      alpha[r] = __expf(m_i[r] - mn);
      m_i[r] = mn;
      rsum[r] = 0.f;
    }
#pragma unroll
    for (int t = 0; t < 4; t++)
#pragma unroll
      for (int r = 0; r < 4; r++) {
        float p = __expf(st[t][r] - m_i[r]);
        st[t][r] = p;
        rsum[r] += p;
      }
#pragma unroll
    for (int off = 1; off < 16; off <<= 1)
#pragma unroll
      for (int r = 0; r < 4; r++) rsum[r] += __shfl_xor(rsum[r], off);
#pragma unroll
    for (int r = 0; r < 4; r++) l_i[r] = l_i[r]*alpha[r] + rsum[r];
#pragma unroll
    for (int v = 0; v < 8; v++)
#pragma unroll
      for (int r = 0; r < 4; r++) o_acc[v][r] *= alpha[r];
    // P (C-layout) -> LDS -> A-layout
#pragma unroll
    for (int t = 0; t < 4; t++)
#pragma unroll
      for (int r = 0; r < 4; r++)
        Ps[wave][(quad*4 + r)*64 + t*16 + lr] = f2b(st[t][r]);
    __syncthreads();
#pragma unroll
    for (int kc = 0; kc < 2; kc++) {
      bf16x8 pa = *(const bf16x8*)(&Ps[wave][lr*64 + kc*32 + quad*8]);
#pragma unroll
      for (int v = 0; v < 8; v++) {
        bf16x8 vf = *(const bf16x8*)(&Vs[(v*16+lr)*64 + kc*32 + quad*8]);
        o_acc[v] = __builtin_amdgcn_mfma_f32_16x16x32_bf16(pa, vf, o_acc[v], 0, 0, 0);
      }
    }
  }
  // epilogue: attn out (B,S,H*128) bf16
  long rowb = q0 + wave*16 + quad*4;
#pragma unroll
  for (int v = 0; v < 8; v++)
#pragma unroll
    for (int r = 0; r < 4; r++) {
      long row = rowb + r;
      O[((long)b*2048 + row)*2048 + h*128 + v*16 + lr] = f2b(o_acc[v][r] / l_i[r]);
    }
}

// ---------------------------------------------------------------- launch
extern "C" void kernel_launch(void* const* d_in, const int* in_sizes, int n_in,
                              void* d_out, int out_size, void* d_ws, size_t ws_size,
                              hipStream_t stream) {
  const float* hidden      = (const float*)d_in[0]; // (2,2048,2048)
  const float* cosb        = (const float*)d_in[1]; // (2,2048,64)
  const float* sinb        = (const float*)d_in[2];
  const float* q_a_W       = (const float*)d_in[3]; // (1536,2048)
  const float* q_a_norm_w  = (const float*)d_in[4]; // (1536,)
  const float* q_b_W       = (const float*)d_in[5]; // (3072,1536)
  const float* kv_a_W      = (const float*)d_in[6]; // (576,2048)
  const float* kv_a_norm_w = (const float*)d_in[7]; // (512,)
  const float* kv_b_W      = (const float*)d_in[8]; // (4096,512)
  const float* o_W         = (const float*)d_in[9]; // (2048,2048)
  float* out = (float*)d_out;

  const int Mrows = 4096; // B*S

  char* ws = (char*)d_ws; size_t off = 0;
  auto alloc = [&](size_t bytes) -> void* {
    void* p = ws + off; off = (off + bytes + 255) & ~(size_t)255; return p;
  };
  BF16* hb   = (BF16*)alloc((size_t)4096*2048*2);
  BF16* Wqa  = (BF16*)alloc((size_t)1536*2048*2);
  BF16* Wqb  = (BF16*)alloc((size_t)3072*1536*2);
  BF16* Wkva = (BF16*)alloc((size_t)576*2048*2);
  BF16* Wkvb = (BF16*)alloc((size_t)4096*512*2);
  BF16* Wo   = (BF16*)alloc((size_t)2048*2048*2);
  float* qa  = (float*)alloc((size_t)4096*1536*4);
  BF16* qan  = (BF16*)alloc((size_t)4096*1536*2);
  float* qb  = (float*)alloc((size_t)4096*3072*4);
  float* ckv = (float*)alloc((size_t)4096*576*4);
  BF16* kvn  = (BF16*)alloc((size_t)4096*512*2);
  BF16* kvb  = (BF16*)alloc((size_t)4096*4096*2);
  BF16* Krot = (BF16*)alloc((size_t)4096*64*2);
  BF16* Qt   = (BF16*)alloc((size_t)2*16*2048*192*2);
  BF16* Kt   = (BF16*)alloc((size_t)2*16*2048*192*2);
  BF16* Vt   = (BF16*)alloc((size_t)2*16*2048*128*2);
  BF16* attn = (BF16*)alloc((size_t)4096*2048*2);

  auto cast = [&](const float* x, BF16* y, long n) {
    cast_bf16_k<<<dim3((unsigned)(n/4/256)), dim3(256), 0, stream>>>(x, y, n);
  };
  cast(hidden, hb,   (long)4096*2048);
  cast(q_a_W,  Wqa,  (long)1536*2048);
  cast(q_b_W,  Wqb,  (long)3072*1536);
  cast(kv_a_W, Wkva, (long)576*2048);
  cast(kv_b_W, Wkvb, (long)4096*512);
  cast(o_W,    Wo,   (long)2048*2048);

  // q_a = hidden @ q_a_W.T  (4096 x 1536, K=2048)
  gemm_nt<false><<<dim3(12, 32), dim3(256), 0, stream>>>(hb, Wqa, qa, Mrows, 1536, 2048);
  rmsnorm_k<1536><<<dim3(4096), dim3(256), 0, stream>>>(qa, q_a_norm_w, qan, 1536, 1536);
  // q = qan @ q_b_W.T  (4096 x 3072, K=1536)
  gemm_nt<false><<<dim3(24, 32), dim3(256), 0, stream>>>(qan, Wqb, qb, Mrows, 3072, 1536);

  // ckv = hidden @ kv_a_W.T  (4096 x 576, K=2048)
  gemm_nt<false><<<dim3(5, 32), dim3(256), 0, stream>>>(hb, Wkva, ckv, Mrows, 576, 2048);
  rmsnorm_k<512><<<dim3(4096), dim3(256), 0, stream>>>(ckv, kv_a_norm_w, kvn, 576, 512);
  prep_krot_k<<<dim3(4096), dim3(64), 0, stream>>>(ckv, cosb, sinb, Krot);
  // kv = kvn @ kv_b_W.T  (4096 x 4096, K=512), bf16 out
  gemm_nt<true><<<dim3(32, 32), dim3(256), 0, stream>>>(kvn, Wkvb, kvb, Mrows, 4096, 512);

  rearrange_kv_k<<<dim3(2048, 16, 2), dim3(64), 0, stream>>>(kvb, Krot, Kt, Vt);
  prep_q_k<<<dim3(2048, 16, 2), dim3(192), 0, stream>>>(qb, cosb, sinb, Qt);

  flash_k<<<dim3(32, 16, 2), dim3(256), 0, stream>>>(Qt, Kt, Vt, attn);

  // out = attn @ o_W.T  (4096 x 2048, K=2048), fp32 out
  gemm_nt<false><<<dim3(16, 32), dim3(256), 0, stream>>>(attn, Wo, out, Mrows, 2048, 2048);
}

// Round 2
// 877.007 us; speedup vs baseline: 1.3893x; 1.3893x over previous
//
#include <hip/hip_runtime.h>
#include <hip/hip_bf16.h>

// DeepSeek V3 MLA attention forward, MI355X (gfx950).
// Constants from reference: B=2, S=2048, D=2048, H=16, NOPE=128, ROPE=64,
// VDIM=128, QKD=192, EPS=1e-6, SCALING=192^-0.5.

typedef __bf16 bf16x8 __attribute__((ext_vector_type(8)));
typedef float floatx4 __attribute__((ext_vector_type(4)));
#define BF16 __hip_bfloat16

static __device__ __forceinline__ BF16 f2b(float x) { return __float2bfloat16(x); }

// ---------------------------------------------------------------- cast f32->bf16
__global__ void cast_bf16_k(const float* __restrict__ x, BF16* __restrict__ y, long n) {
  long i = ((long)blockIdx.x * 256 + threadIdx.x) * 4;
  if (i + 3 < n) {
    float4 v = *(const float4*)(x + i);
    y[i+0] = f2b(v.x); y[i+1] = f2b(v.y); y[i+2] = f2b(v.z); y[i+3] = f2b(v.w);
  }
}

// ---------------------------------------------------------------- NT GEMM
// C[M][N] = A[M][K] * B[N][K]^T, bf16 in, fp32 accumulate.
// 256 threads = 4 waves (2x2), 128x128 block tile, 64x64 per wave (4x4 mfma tiles).
template<bool OUT_BF16>
__global__ __launch_bounds__(256) void gemm_nt(const BF16* __restrict__ A, const BF16* __restrict__ B,
                                               void* __restrict__ C, int M, int N, int K) {
  int tid = threadIdx.x;
  int wave = tid >> 6, lane = tid & 63;
  int wr = wave >> 1, wc = wave & 1;
  int lr = lane & 15, quad = lane >> 4;
  long m0 = (long)blockIdx.y * 128 + wr * 64;
  long n0 = (long)blockIdx.x * 128 + wc * 64;
  floatx4 acc[4][4] = {};
  for (int k0 = 0; k0 < K; k0 += 32) {
    bf16x8 a[4], b[4];
#pragma unroll
    for (int i = 0; i < 4; i++) {
      long r = m0 + i*16 + lr; if (r >= M) r = M - 1;
      a[i] = *(const bf16x8*)(A + r*(long)K + k0 + quad*8);
    }
#pragma unroll
    for (int j = 0; j < 4; j++) {
      long c = n0 + j*16 + lr; if (c >= N) c = N - 1;
      b[j] = *(const bf16x8*)(B + c*(long)K + k0 + quad*8);
    }
#pragma unroll
    for (int i = 0; i < 4; i++)
#pragma unroll
      for (int j = 0; j < 4; j++)
        acc[i][j] = __builtin_amdgcn_mfma_f32_16x16x32_bf16(a[i], b[j], acc[i][j], 0, 0, 0);
  }
#pragma unroll
  for (int i = 0; i < 4; i++)
#pragma unroll
    for (int j = 0; j < 4; j++) {
      long col = n0 + j*16 + lr;
      if (col < N) {
#pragma unroll
        for (int r = 0; r < 4; r++) {
          long row = m0 + i*16 + quad*4 + r;
          if (row < M) {
            if (OUT_BF16) ((BF16*)C)[row*(long)N + col] = f2b(acc[i][j][r]);
            else          ((float*)C)[row*(long)N + col] = acc[i][j][r];
          }
        }
      }
    }
}

// ---------------------------------------------------------------- RMSNorm (row-wise), fp32 in, bf16 out
template<int D>
__global__ __launch_bounds__(256) void rmsnorm_k(const float* __restrict__ x, const float* __restrict__ w,
                                                 BF16* __restrict__ y, int ld_in, int ld_out) {
  long row = blockIdx.x;
  const float* xr = x + row * (long)ld_in;
  float ss = 0.f;
  for (int i = threadIdx.x * 4; i < D; i += 1024) {
    float4 v = *(const float4*)(xr + i);
    ss += v.x*v.x + v.y*v.y + v.z*v.z + v.w*v.w;
  }
#pragma unroll
  for (int off = 32; off > 0; off >>= 1) ss += __shfl_down(ss, off);
  __shared__ float red[4];
  if ((threadIdx.x & 63) == 0) red[threadIdx.x >> 6] = ss;
  __syncthreads();
  float tot = red[0] + red[1] + red[2] + red[3];
  float rs = rsqrtf(tot / (float)D + 1e-6f);
  BF16* yr = y + row * (long)ld_out;
  for (int i = threadIdx.x * 4; i < D; i += 1024) {
    float4 v = *(const float4*)(xr + i);
    yr[i+0] = f2b(v.x * w[i+0] * rs);
    yr[i+1] = f2b(v.y * w[i+1] * rs);
    yr[i+2] = f2b(v.z * w[i+2] * rs);
    yr[i+3] = f2b(v.w * w[i+3] * rs);
  }
}

// ---------------------------------------------------------------- RoPE on q, gather to (B,H,S,192) bf16
__global__ void prep_q_k(const float* __restrict__ q, const float* __restrict__ cosb,
                         const float* __restrict__ sinb, BF16* __restrict__ Qt) {
  // grid (S, H, B), block 192
  int s = blockIdx.x, h = blockIdx.y, b = blockIdx.z, d = threadIdx.x;
  long row = (long)b * 2048 + s;
  const float* qr = q + row * 3072 + h * 192;
  float val;
  if (d < 128) {
    val = qr[d];
  } else {
    int i = d - 128;
    float x = qr[d];
    float rot = (i < 32) ? -qr[128 + i + 32] : qr[128 + i - 32];
    val = x * cosb[row*64 + i] + rot * sinb[row*64 + i];
  }
  Qt[(((long)b*16 + h)*2048 + s)*192 + d] = f2b(val);
}

// ---------------------------------------------------------------- RoPE on k_rot (per b,s), bf16 out
__global__ void prep_krot_k(const float* __restrict__ ckv, const float* __restrict__ cosb,
                            const float* __restrict__ sinb, BF16* __restrict__ Krot) {
  // grid 4096, block 64
  long row = blockIdx.x; int i = threadIdx.x;
  const float* kr = ckv + row * 576 + 512;
  float x = kr[i];
  float rot = (i < 32) ? -kr[i + 32] : kr[i - 32];
  Krot[row*64 + i] = f2b(x * cosb[row*64 + i] + rot * sinb[row*64 + i]);
}

// ---------------------------------------------------------------- gather kv -> K (B,H,S,192), V (B,H,S,128)
__global__ void rearrange_kv_k(const BF16* __restrict__ kv, const BF16* __restrict__ Krot,
                               BF16* __restrict__ Kt, BF16* __restrict__ Vt) {
  // grid (S, H, B), block 64
  int s = blockIdx.x, h = blockIdx.y, b = blockIdx.z, t = threadIdx.x;
  long row = (long)b * 2048 + s;
  const BF16* src = kv + row * 4096 + h * 256;
  long kbase = (((long)b*16 + h)*2048 + s) * 192;
  long vbase = (((long)b*16 + h)*2048 + s) * 128;
  for (int d = t; d < 128; d += 64) {
    Kt[kbase + d] = src[d];
    Vt[vbase + d] = src[128 + d];
  }
  Kt[kbase + 128 + t] = Krot[row*64 + t];
}

// ---------------------------------------------------------------- causal flash attention
// grid (16, H, B); 256 threads = 4 waves; each block handles the q-tile PAIR
// {blockIdx.x, 31-blockIdx.x} (33 k-tiles total -> perfect load balance).
// LDS row strides padded +8 bf16 (stride = 4 dw mod 32) -> bank-uniform b128.
#define LK 200   // Ks row stride (192+8)
#define LV 72    // Vs row stride (64+8)
#define LP 72    // Ps row stride (64+8)
__global__ __launch_bounds__(256) void flash_k(const BF16* __restrict__ Qt, const BF16* __restrict__ Kt,
                                               const BF16* __restrict__ Vt, BF16* __restrict__ O) {
  __shared__ __align__(16) BF16 Ks[64*LK];    // K tile [kpos][d]
  __shared__ __align__(16) BF16 Vs[128*LV];   // V tile transposed [vd][kpos]
  __shared__ __align__(16) BF16 Ps[4][16*LP]; // per-wave P [q][kpos]
  int tid = threadIdx.x, wave = tid >> 6, lane = tid & 63;
  int lr = lane & 15, quad = lane >> 4;
  int b = blockIdx.z, h = blockIdx.y;
  const BF16* Qb = Qt + ((long)(b*16 + h) * 2048) * 192;
  const BF16* Kb = Kt + ((long)(b*16 + h) * 2048) * 192;
  const BF16* Vb = Vt + ((long)(b*16 + h) * 2048) * 128;
  const float NEG_INF = -__builtin_inff();
  const float scale = 0.07216878364870322f; // 192^-0.5

  for (int half = 0; half < 2; half++) {
    int qt = (half == 0) ? (int)blockIdx.x : 31 - (int)blockIdx.x;
    int q0 = qt * 64;
    bf16x8 qf[6];
    {
      const BF16* qp = Qb + (long)(q0 + wave*16 + lr) * 192 + quad*8;
#pragma unroll
      for (int f = 0; f < 6; f++) qf[f] = *(const bf16x8*)(qp + f*32);
    }
    float m_i[4], l_i[4];
#pragma unroll
    for (int r = 0; r < 4; r++) { m_i[r] = NEG_INF; l_i[r] = 0.f; }
    floatx4 o_acc[8] = {};
    int nk = qt + 1;
    for (int kt = 0; kt < nk; kt++) {
      int k0 = kt * 64;
      __syncthreads(); // protect prev-iter LDS reads before restaging
      for (int c = tid; c < 1536; c += 256) {  // 64x192 K tile, 16B chunks
        int row = c / 24, col = (c % 24) * 8;
        *(bf16x8*)(Ks + row*LK + col) = *(const bf16x8*)(Kb + (long)(k0+row)*192 + col);
      }
      // V tile -> transposed [vd][kpos]; kpos = lane so scalar LDS writes are
      // consecutive-column within a wave (2-way at worst = free).
#pragma unroll
      for (int it = 0; it < 4; it++) {
        int kpos = lane;
        int vd0 = (wave + it*4) * 8;
        bf16x8 v = *(const bf16x8*)(Vb + (long)(k0+kpos)*128 + vd0);
#pragma unroll
        for (int j = 0; j < 8; j++) Vs[(vd0+j)*LV + kpos] = ((BF16*)&v)[j];
      }
      __syncthreads();
      // scores: 16 q rows x 64 k cols = 4 C tiles
      floatx4 st[4];
#pragma unroll
      for (int t = 0; t < 4; t++) {
        floatx4 c = {};
#pragma unroll
        for (int f = 0; f < 6; f++) {
          bf16x8 kf = *(const bf16x8*)(Ks + (t*16+lr)*LK + f*32 + quad*8);
          c = __builtin_amdgcn_mfma_f32_16x16x32_bf16(qf[f], kf, c, 0, 0, 0);
        }
        st[t] = c;
      }
      int rowbase = q0 + wave*16 + quad*4;
      float mt[4];
#pragma unroll
      for (int r = 0; r < 4; r++) mt[r] = NEG_INF;
#pragma unroll
      for (int t = 0; t < 4; t++) {
        int col = k0 + t*16 + lr;
#pragma unroll
        for (int r = 0; r < 4; r++) {
          float s = st[t][r] * scale;
          if (col > rowbase + r) s = NEG_INF;
          st[t][r] = s;
          mt[r] = fmaxf(mt[r], s);
        }
      }
#pragma unroll
      for (int off = 1; off < 16; off <<= 1)
#pragma unroll
        for (int r = 0; r < 4; r++) mt[r] = fmaxf(mt[r], __shfl_xor(mt[r], off));
      float alpha[4], rsum[4];
#pragma unroll
      for (int r = 0; r < 4; r++) {
        float mn = fmaxf(m_i[r], mt[r]);
        alpha[r] = __expf(m_i[r] - mn);
        m_i[r] = mn;
        rsum[r] = 0.f;
      }
#pragma unroll
      for (int t = 0; t < 4; t++)
#pragma unroll
        for (int r = 0; r < 4; r++) {
          float p = __expf(st[t][r] - m_i[r]);
          st[t][r] = p;
          rsum[r] += p;
        }
#pragma unroll
      for (int off = 1; off < 16; off <<= 1)
#pragma unroll
        for (int r = 0; r < 4; r++) rsum[r] += __shfl_xor(rsum[r], off);
#pragma unroll
      for (int r = 0; r < 4; r++) l_i[r] = l_i[r]*alpha[r] + rsum[r];
#pragma unroll
      for (int v = 0; v < 8; v++)
#pragma unroll
        for (int r = 0; r < 4; r++) o_acc[v][r] *= alpha[r];
      // P (C-layout) -> LDS -> A-layout. Ps is wave-private: no barrier needed,
      // wave-level LDS RAW ordering is automatic (compiler lgkmcnt).
#pragma unroll
      for (int t = 0; t < 4; t++)
#pragma unroll
        for (int r = 0; r < 4; r++)
          Ps[wave][(quad*4 + r)*LP + t*16 + lr] = f2b(st[t][r]);
#pragma unroll
      for (int kc = 0; kc < 2; kc++) {
        bf16x8 pa = *(const bf16x8*)(&Ps[wave][lr*LP + kc*32 + quad*8]);
#pragma unroll
        for (int v = 0; v < 8; v++) {
          bf16x8 vf = *(const bf16x8*)(&Vs[(v*16+lr)*LV + kc*32 + quad*8]);
          o_acc[v] = __builtin_amdgcn_mfma_f32_16x16x32_bf16(pa, vf, o_acc[v], 0, 0, 0);
        }
      }
    }
    // epilogue: attn out (B,S,H*128) bf16
    long rowb = q0 + wave*16 + quad*4;
#pragma unroll
    for (int v = 0; v < 8; v++)
#pragma unroll
      for (int r = 0; r < 4; r++) {
        long row = rowb + r;
        O[((long)b*2048 + row)*2048 + h*128 + v*16 + lr] = f2b(o_acc[v][r] / l_i[r]);
      }
  }
}

// ---------------------------------------------------------------- launch
extern "C" void kernel_launch(void* const* d_in, const int* in_sizes, int n_in,
                              void* d_out, int out_size, void* d_ws, size_t ws_size,
                              hipStream_t stream) {
  const float* hidden      = (const float*)d_in[0]; // (2,2048,2048)
  const float* cosb        = (const float*)d_in[1]; // (2,2048,64)
  const float* sinb        = (const float*)d_in[2];
  const float* q_a_W       = (const float*)d_in[3]; // (1536,2048)
  const float* q_a_norm_w  = (const float*)d_in[4]; // (1536,)
  const float* q_b_W       = (const float*)d_in[5]; // (3072,1536)
  const float* kv_a_W      = (const float*)d_in[6]; // (576,2048)
  const float* kv_a_norm_w = (const float*)d_in[7]; // (512,)
  const float* kv_b_W      = (const float*)d_in[8]; // (4096,512)
  const float* o_W         = (const float*)d_in[9]; // (2048,2048)
  float* out = (float*)d_out;

  const int Mrows = 4096; // B*S

  char* ws = (char*)d_ws; size_t off = 0;
  auto alloc = [&](size_t bytes) -> void* {
    void* p = ws + off; off = (off + bytes + 255) & ~(size_t)255; return p;
  };
  BF16* hb   = (BF16*)alloc((size_t)4096*2048*2);
  BF16* Wqa  = (BF16*)alloc((size_t)1536*2048*2);
  BF16* Wqb  = (BF16*)alloc((size_t)3072*1536*2);
  BF16* Wkva = (BF16*)alloc((size_t)576*2048*2);
  BF16* Wkvb = (BF16*)alloc((size_t)4096*512*2);
  BF16* Wo   = (BF16*)alloc((size_t)2048*2048*2);
  float* qa  = (float*)alloc((size_t)4096*1536*4);
  BF16* qan  = (BF16*)alloc((size_t)4096*1536*2);
  float* qb  = (float*)alloc((size_t)4096*3072*4);
  float* ckv = (float*)alloc((size_t)4096*576*4);
  BF16* kvn  = (BF16*)alloc((size_t)4096*512*2);
  BF16* kvb  = (BF16*)alloc((size_t)4096*4096*2);
  BF16* Krot = (BF16*)alloc((size_t)4096*64*2);
  BF16* Qt   = (BF16*)alloc((size_t)2*16*2048*192*2);
  BF16* Kt   = (BF16*)alloc((size_t)2*16*2048*192*2);
  BF16* Vt   = (BF16*)alloc((size_t)2*16*2048*128*2);
  BF16* attn = (BF16*)alloc((size_t)4096*2048*2);

  auto cast = [&](const float* x, BF16* y, long n) {
    cast_bf16_k<<<dim3((unsigned)(n/4/256)), dim3(256), 0, stream>>>(x, y, n);
  };
  cast(hidden, hb,   (long)4096*2048);
  cast(q_a_W,  Wqa,  (long)1536*2048);
  cast(q_b_W,  Wqb,  (long)3072*1536);
  cast(kv_a_W, Wkva, (long)576*2048);
  cast(kv_b_W, Wkvb, (long)4096*512);
  cast(o_W,    Wo,   (long)2048*2048);

  // q_a = hidden @ q_a_W.T  (4096 x 1536, K=2048)
  gemm_nt<false><<<dim3(12, 32), dim3(256), 0, stream>>>(hb, Wqa, qa, Mrows, 1536, 2048);
  rmsnorm_k<1536><<<dim3(4096), dim3(256), 0, stream>>>(qa, q_a_norm_w, qan, 1536, 1536);
  // q = qan @ q_b_W.T  (4096 x 3072, K=1536)
  gemm_nt<false><<<dim3(24, 32), dim3(256), 0, stream>>>(qan, Wqb, qb, Mrows, 3072, 1536);

  // ckv = hidden @ kv_a_W.T  (4096 x 576, K=2048)
  gemm_nt<false><<<dim3(5, 32), dim3(256), 0, stream>>>(hb, Wkva, ckv, Mrows, 576, 2048);
  rmsnorm_k<512><<<dim3(4096), dim3(256), 0, stream>>>(ckv, kv_a_norm_w, kvn, 576, 512);
  prep_krot_k<<<dim3(4096), dim3(64), 0, stream>>>(ckv, cosb, sinb, Krot);
  // kv = kvn @ kv_b_W.T  (4096 x 4096, K=512), bf16 out
  gemm_nt<true><<<dim3(32, 32), dim3(256), 0, stream>>>(kvn, Wkvb, kvb, Mrows, 4096, 512);

  rearrange_kv_k<<<dim3(2048, 16, 2), dim3(64), 0, stream>>>(kvb, Krot, Kt, Vt);
  prep_q_k<<<dim3(2048, 16, 2), dim3(192), 0, stream>>>(qb, cosb, sinb, Qt);

  flash_k<<<dim3(16, 16, 2), dim3(256), 0, stream>>>(Qt, Kt, Vt, attn);

  // out = attn @ o_W.T  (4096 x 2048, K=2048), fp32 out
  gemm_nt<false><<<dim3(16, 32), dim3(256), 0, stream>>>(attn, Wo, out, Mrows, 2048, 2048);
}

// Round 3
// 594.917 us; speedup vs baseline: 2.0480x; 1.4742x over previous
//
#include <hip/hip_runtime.h>
#include <hip/hip_bf16.h>

// DeepSeek V3 MLA attention forward, MI355X (gfx950).
// B=2, S=2048, D=2048, H=16, NOPE=128, ROPE=64, VDIM=128, QKD=192.

typedef __bf16 bf16x8 __attribute__((ext_vector_type(8)));
typedef float floatx4 __attribute__((ext_vector_type(4)));
#define BF16 __hip_bfloat16

static __device__ __forceinline__ BF16 f2b(float x) { return __float2bfloat16(x); }

static __device__ __forceinline__ void load_lds16(const BF16* g, BF16* l) {
  __builtin_amdgcn_global_load_lds((__attribute__((address_space(1))) void*)(void*)g,
                                   (__attribute__((address_space(3))) void*)(void*)l,
                                   16, 0, 0);
}

// ---------------------------------------------------------------- cast f32->bf16
__global__ void cast_bf16_k(const float* __restrict__ x, BF16* __restrict__ y, long n) {
  long i = ((long)blockIdx.x * 256 + threadIdx.x) * 4;
  if (i + 3 < n) {
    float4 v = *(const float4*)(x + i);
    y[i+0] = f2b(v.x); y[i+1] = f2b(v.y); y[i+2] = f2b(v.z); y[i+3] = f2b(v.w);
  }
}

// ---------------------------------------------------------------- NT GEMM, m97-style LDS staging
// C[M][N] = A[M][K]*B[N][K]^T. 256 thr = 4 waves (2x2), 128x128 tile, BK=32.
// global_load_lds width-16 staging; unpadded [128][32] LDS (bank-uniform b128 reads).
// OUT_MODE: 0 = fp32 C;  2 = kv scatter -> Kt/Vt;  3 = q RoPE+scale scatter -> Qt.
template<int OUT_MODE>
__global__ __launch_bounds__(256) void gemm_lds(const BF16* __restrict__ A, const BF16* __restrict__ B,
                                                void* __restrict__ C, int M, int N, int K,
                                                const float* __restrict__ cosb,
                                                const float* __restrict__ sinb,
                                                BF16* __restrict__ P1, BF16* __restrict__ P2) {
  __shared__ __align__(16) BF16 As[128*32];
  __shared__ __align__(16) BF16 Bs[128*32];
  int tid = threadIdx.x, wave = tid >> 6, lane = tid & 63;
  int wr = wave >> 1, wc = wave & 1, lr = lane & 15, quad = lane >> 4;
  long m0 = (long)blockIdx.y * 128, n0 = (long)blockIdx.x * 128;

  // staging: 512 16B-chunks per tile; chunk c -> row c>>2, elem off (c&3)*8.
  int c0 = wave*64 + lane, c1 = c0 + 256;
  const BF16* ga0 = A + (m0 + (c0>>2))*(long)K + (c0&3)*8;
  const BF16* ga1 = A + (m0 + (c1>>2))*(long)K + (c1&3)*8;
  long bn0 = n0 + (c0>>2); if (bn0 >= N) bn0 = N-1;
  long bn1 = n0 + (c1>>2); if (bn1 >= N) bn1 = N-1;
  const BF16* gb0 = B + bn0*(long)K + (c0&3)*8;
  const BF16* gb1 = B + bn1*(long)K + (c1&3)*8;
  BF16* la0 = As + wave*512;        // wave-uniform LDS bases (chunkbase*8)
  BF16* la1 = As + wave*512 + 2048;
  BF16* lb0 = Bs + wave*512;
  BF16* lb1 = Bs + wave*512 + 2048;

  floatx4 acc[4][4] = {};
  for (int k0 = 0; k0 < K; k0 += 32) {
    __syncthreads();
    load_lds16(ga0 + k0, la0);
    load_lds16(ga1 + k0, la1);
    load_lds16(gb0 + k0, lb0);
    load_lds16(gb1 + k0, lb1);
    __syncthreads();
    bf16x8 a[4], b[4];
#pragma unroll
    for (int i = 0; i < 4; i++) a[i] = *(const bf16x8*)(As + (wr*64 + i*16 + lr)*32 + quad*8);
#pragma unroll
    for (int j = 0; j < 4; j++) b[j] = *(const bf16x8*)(Bs + (wc*64 + j*16 + lr)*32 + quad*8);
#pragma unroll
    for (int i = 0; i < 4; i++)
#pragma unroll
      for (int j = 0; j < 4; j++)
        acc[i][j] = __builtin_amdgcn_mfma_f32_16x16x32_bf16(a[i], b[j], acc[i][j], 0, 0, 0);
  }

  long n0w = n0 + wc*64;
  const float SCALE = 0.07216878364870322f; // 192^-0.5
#pragma unroll
  for (int i = 0; i < 4; i++) {
#pragma unroll
    for (int r = 0; r < 4; r++) {
      long row = m0 + wr*64 + i*16 + quad*4 + r;
      long b = row >> 11, s = row & 2047;
      if (OUT_MODE == 0) {
#pragma unroll
        for (int j = 0; j < 4; j++) {
          long col = n0w + j*16 + lr;
          if (col < N) ((float*)C)[row*(long)N + col] = acc[i][j][r];
        }
      } else if (OUT_MODE == 2) {
        // kv scatter: col = 256h + d; d<128 -> Kt[...,d], else Vt[...,d-128]
#pragma unroll
        for (int j = 0; j < 4; j++) {
          long col = n0w + j*16 + lr;
          long h = col >> 8, d = col & 255;
          long base = (b*16 + h)*2048 + s;
          if (d < 128) P1[base*192 + d] = f2b(acc[i][j][r]);
          else         P2[base*128 + d - 128] = f2b(acc[i][j][r]);
        }
      } else { // OUT_MODE == 3: q RoPE + SCALING -> Qt (B,H,S,192)
        bool rope = ((n0w % 192) == 128); // whole 64-col window is the rope block
#pragma unroll
        for (int j = 0; j < 4; j++) {
          long col = n0w + j*16 + lr;
          float x = acc[i][j][r], val;
          if (rope) {
            int id = j*16 + lr;                 // 0..63 within rope block
            float partner = acc[i][j^2][r];
            float rot = (j < 2) ? -partner : partner;
            val = x*cosb[row*64 + id] + rot*sinb[row*64 + id];
          } else {
            val = x;
          }
          long h = col / 192, d = col % 192;
          P1[((b*16 + h)*2048 + s)*192 + d] = f2b(val * SCALE);
        }
      }
    }
  }
}

// ---------------------------------------------------------------- RMSNorm (row-wise), fp32 in, bf16 out
template<int D>
__global__ __launch_bounds__(256) void rmsnorm_k(const float* __restrict__ x, const float* __restrict__ w,
                                                 BF16* __restrict__ y, int ld_in, int ld_out) {
  long row = blockIdx.x;
  const float* xr = x + row * (long)ld_in;
  float ss = 0.f;
  for (int i = threadIdx.x * 4; i < D; i += 1024) {
    float4 v = *(const float4*)(xr + i);
    ss += v.x*v.x + v.y*v.y + v.z*v.z + v.w*v.w;
  }
#pragma unroll
  for (int off = 32; off > 0; off >>= 1) ss += __shfl_down(ss, off);
  __shared__ float red[4];
  if ((threadIdx.x & 63) == 0) red[threadIdx.x >> 6] = ss;
  __syncthreads();
  float tot = red[0] + red[1] + red[2] + red[3];
  float rs = rsqrtf(tot / (float)D + 1e-6f);
  BF16* yr = y + row * (long)ld_out;
  for (int i = threadIdx.x * 4; i < D; i += 1024) {
    float4 v = *(const float4*)(xr + i);
    yr[i+0] = f2b(v.x * w[i+0] * rs);
    yr[i+1] = f2b(v.y * w[i+1] * rs);
    yr[i+2] = f2b(v.z * w[i+2] * rs);
    yr[i+3] = f2b(v.w * w[i+3] * rs);
  }
}

// ---------------------------------------------------------------- RoPE on k_rot -> Kt[...,128:192] for all 16 heads
__global__ void prep_krot_k(const float* __restrict__ ckv, const float* __restrict__ cosb,
                            const float* __restrict__ sinb, BF16* __restrict__ Kt) {
  // grid 4096, block 64
  long row = blockIdx.x; int i = threadIdx.x;
  const float* kr = ckv + row * 576 + 512;
  float x = kr[i];
  float rot = (i < 32) ? -kr[i + 32] : kr[i - 32];
  BF16 v = f2b(x * cosb[row*64 + i] + rot * sinb[row*64 + i]);
  long b = row >> 11, s = row & 2047;
  long base = ((b*16)*2048 + s)*192 + 128 + i;
#pragma unroll
  for (int h = 0; h < 16; h++) Kt[base + (long)h*2048*192] = v;
}

// ---------------------------------------------------------------- causal flash attention
// grid (16, H, B); block handles q-tile pair {x, 31-x} (33 k-tiles, balanced).
// Q is prescaled by 192^-0.5. Mask applied only on the diagonal k-tile.
#define LK 200
#define LV 72
#define LP 72
__global__ __launch_bounds__(256) void flash_k(const BF16* __restrict__ Qt, const BF16* __restrict__ Kt,
                                               const BF16* __restrict__ Vt, BF16* __restrict__ O) {
  __shared__ __align__(16) BF16 Ks[64*LK];
  __shared__ __align__(16) BF16 Vs[128*LV];
  __shared__ __align__(16) BF16 Ps[4][16*LP];
  int tid = threadIdx.x, wave = tid >> 6, lane = tid & 63;
  int lr = lane & 15, quad = lane >> 4;
  int b = blockIdx.z, h = blockIdx.y;
  const BF16* Qb = Qt + ((long)(b*16 + h) * 2048) * 192;
  const BF16* Kb = Kt + ((long)(b*16 + h) * 2048) * 192;
  const BF16* Vb = Vt + ((long)(b*16 + h) * 2048) * 128;
  const float NEG_INF = -__builtin_inff();

  for (int half = 0; half < 2; half++) {
    int qt = (half == 0) ? (int)blockIdx.x : 31 - (int)blockIdx.x;
    int q0 = qt * 64;
    bf16x8 qf[6];
    {
      const BF16* qp = Qb + (long)(q0 + wave*16 + lr) * 192 + quad*8;
#pragma unroll
      for (int f = 0; f < 6; f++) qf[f] = *(const bf16x8*)(qp + f*32);
    }
    float m_i[4], l_i[4];
#pragma unroll
    for (int r = 0; r < 4; r++) { m_i[r] = NEG_INF; l_i[r] = 0.f; }
    floatx4 o_acc[8] = {};
    int nk = qt + 1;
    for (int kt = 0; kt < nk; kt++) {
      int k0 = kt * 64;
      __syncthreads();
      for (int c = tid; c < 1536; c += 256) {
        int row = c / 24, col = (c % 24) * 8;
        *(bf16x8*)(Ks + row*LK + col) = *(const bf16x8*)(Kb + (long)(k0+row)*192 + col);
      }
#pragma unroll
      for (int it = 0; it < 4; it++) {
        int kpos = lane;
        int vd0 = (wave + it*4) * 8;
        bf16x8 v = *(const bf16x8*)(Vb + (long)(k0+kpos)*128 + vd0);
#pragma unroll
        for (int j = 0; j < 8; j++) Vs[(vd0+j)*LV + kpos] = ((BF16*)&v)[j];
      }
      __syncthreads();
      floatx4 st[4];
#pragma unroll
      for (int t = 0; t < 4; t++) {
        floatx4 c = {};
#pragma unroll
        for (int f = 0; f < 6; f++) {
          bf16x8 kf = *(const bf16x8*)(Ks + (t*16+lr)*LK + f*32 + quad*8);
          c = __builtin_amdgcn_mfma_f32_16x16x32_bf16(qf[f], kf, c, 0, 0, 0);
        }
        st[t] = c;
      }
      int rowbase = q0 + wave*16 + quad*4;
      float mt[4];
#pragma unroll
      for (int r = 0; r < 4; r++) mt[r] = NEG_INF;
      if (kt == qt) { // diagonal tile: causal mask
#pragma unroll
        for (int t = 0; t < 4; t++) {
          int col = k0 + t*16 + lr;
#pragma unroll
          for (int r = 0; r < 4; r++) {
            float s = st[t][r];
            if (col > rowbase + r) s = NEG_INF;
            st[t][r] = s;
            mt[r] = fmaxf(mt[r], s);
          }
        }
      } else {
#pragma unroll
        for (int t = 0; t < 4; t++)
#pragma unroll
          for (int r = 0; r < 4; r++) mt[r] = fmaxf(mt[r], st[t][r]);
      }
#pragma unroll
      for (int off = 1; off < 16; off <<= 1)
#pragma unroll
        for (int r = 0; r < 4; r++) mt[r] = fmaxf(mt[r], __shfl_xor(mt[r], off));
      float alpha[4], rsum[4];
#pragma unroll
      for (int r = 0; r < 4; r++) {
        float mn = fmaxf(m_i[r], mt[r]);
        alpha[r] = __expf(m_i[r] - mn);
        m_i[r] = mn;
        rsum[r] = 0.f;
      }
#pragma unroll
      for (int t = 0; t < 4; t++)
#pragma unroll
        for (int r = 0; r < 4; r++) {
          float p = __expf(st[t][r] - m_i[r]);
          st[t][r] = p;
          rsum[r] += p;
        }
#pragma unroll
      for (int off = 1; off < 16; off <<= 1)
#pragma unroll
        for (int r = 0; r < 4; r++) rsum[r] += __shfl_xor(rsum[r], off);
#pragma unroll
      for (int r = 0; r < 4; r++) l_i[r] = l_i[r]*alpha[r] + rsum[r];
#pragma unroll
      for (int v = 0; v < 8; v++)
#pragma unroll
        for (int r = 0; r < 4; r++) o_acc[v][r] *= alpha[r];
      // P (C-layout) -> wave-private LDS -> A-layout (no barrier needed)
#pragma unroll
      for (int t = 0; t < 4; t++)
#pragma unroll
        for (int r = 0; r < 4; r++)
          Ps[wave][(quad*4 + r)*LP + t*16 + lr] = f2b(st[t][r]);
#pragma unroll
      for (int kc = 0; kc < 2; kc++) {
        bf16x8 pa = *(const bf16x8*)(&Ps[wave][lr*LP + kc*32 + quad*8]);
#pragma unroll
        for (int v = 0; v < 8; v++) {
          bf16x8 vf = *(const bf16x8*)(&Vs[(v*16+lr)*LV + kc*32 + quad*8]);
          o_acc[v] = __builtin_amdgcn_mfma_f32_16x16x32_bf16(pa, vf, o_acc[v], 0, 0, 0);
        }
      }
    }
    long rowb = q0 + wave*16 + quad*4;
#pragma unroll
    for (int v = 0; v < 8; v++)
#pragma unroll
      for (int r = 0; r < 4; r++) {
        long row = rowb + r;
        O[((long)b*2048 + row)*2048 + h*128 + v*16 + lr] = f2b(o_acc[v][r] / l_i[r]);
      }
  }
}

// ---------------------------------------------------------------- launch
extern "C" void kernel_launch(void* const* d_in, const int* in_sizes, int n_in,
                              void* d_out, int out_size, void* d_ws, size_t ws_size,
                              hipStream_t stream) {
  const float* hidden      = (const float*)d_in[0];
  const float* cosb        = (const float*)d_in[1];
  const float* sinb        = (const float*)d_in[2];
  const float* q_a_W       = (const float*)d_in[3];
  const float* q_a_norm_w  = (const float*)d_in[4];
  const float* q_b_W       = (const float*)d_in[5];
  const float* kv_a_W      = (const float*)d_in[6];
  const float* kv_a_norm_w = (const float*)d_in[7];
  const float* kv_b_W      = (const float*)d_in[8];
  const float* o_W         = (const float*)d_in[9];
  float* out = (float*)d_out;

  const int Mrows = 4096;

  char* ws = (char*)d_ws; size_t off = 0;
  auto alloc = [&](size_t bytes) -> void* {
    void* p = ws + off; off = (off + bytes + 255) & ~(size_t)255; return p;
  };
  BF16* hb   = (BF16*)alloc((size_t)4096*2048*2);
  BF16* Wqa  = (BF16*)alloc((size_t)1536*2048*2);
  BF16* Wqb  = (BF16*)alloc((size_t)3072*1536*2);
  BF16* Wkva = (BF16*)alloc((size_t)576*2048*2);
  BF16* Wkvb = (BF16*)alloc((size_t)4096*512*2);
  BF16* Wo   = (BF16*)alloc((size_t)2048*2048*2);
  float* qa  = (float*)alloc((size_t)4096*1536*4);
  BF16* qan  = (BF16*)alloc((size_t)4096*1536*2);
  float* ckv = (float*)alloc((size_t)4096*576*4);
  BF16* kvn  = (BF16*)alloc((size_t)4096*512*2);
  BF16* Qt   = (BF16*)alloc((size_t)2*16*2048*192*2);
  BF16* Kt   = (BF16*)alloc((size_t)2*16*2048*192*2);
  BF16* Vt   = (BF16*)alloc((size_t)2*16*2048*128*2);
  BF16* attn = (BF16*)alloc((size_t)4096*2048*2);

  auto cast = [&](const float* x, BF16* y, long n) {
    cast_bf16_k<<<dim3((unsigned)(n/4/256)), dim3(256), 0, stream>>>(x, y, n);
  };
  cast(hidden, hb,   (long)4096*2048);
  cast(q_a_W,  Wqa,  (long)1536*2048);
  cast(q_b_W,  Wqb,  (long)3072*1536);
  cast(kv_a_W, Wkva, (long)576*2048);
  cast(kv_b_W, Wkvb, (long)4096*512);
  cast(o_W,    Wo,   (long)2048*2048);

  // q_a = hidden @ q_a_W.T (4096x1536, K=2048), fp32
  gemm_lds<0><<<dim3(12, 32), dim3(256), 0, stream>>>(hb, Wqa, qa, Mrows, 1536, 2048,
                                                      nullptr, nullptr, nullptr, nullptr);
  rmsnorm_k<1536><<<dim3(4096), dim3(256), 0, stream>>>(qa, q_a_norm_w, qan, 1536, 1536);
  // q = qan @ q_b_W.T (4096x3072, K=1536), fused RoPE+scale -> Qt
  gemm_lds<3><<<dim3(24, 32), dim3(256), 0, stream>>>(qan, Wqb, nullptr, Mrows, 3072, 1536,
                                                      cosb, sinb, Qt, nullptr);

  // ckv = hidden @ kv_a_W.T (4096x576, K=2048), fp32
  gemm_lds<0><<<dim3(5, 32), dim3(256), 0, stream>>>(hb, Wkva, ckv, Mrows, 576, 2048,
                                                     nullptr, nullptr, nullptr, nullptr);
  rmsnorm_k<512><<<dim3(4096), dim3(256), 0, stream>>>(ckv, kv_a_norm_w, kvn, 576, 512);
  prep_krot_k<<<dim3(4096), dim3(64), 0, stream>>>(ckv, cosb, sinb, Kt);
  // kv = kvn @ kv_b_W.T (4096x4096, K=512), fused scatter -> Kt/Vt
  gemm_lds<2><<<dim3(32, 32), dim3(256), 0, stream>>>(kvn, Wkvb, nullptr, Mrows, 4096, 512,
                                                      nullptr, nullptr, Kt, Vt);

  flash_k<<<dim3(16, 16, 2), dim3(256), 0, stream>>>(Qt, Kt, Vt, attn);

  // out = attn @ o_W.T (4096x2048, K=2048), fp32 -> d_out
  gemm_lds<0><<<dim3(16, 32), dim3(256), 0, stream>>>(attn, Wo, out, Mrows, 2048, 2048,
                                                      nullptr, nullptr, nullptr, nullptr);
}

// Round 4
// 504.094 us; speedup vs baseline: 2.4170x; 1.1802x over previous
//
#include <hip/hip_runtime.h>
#include <hip/hip_bf16.h>

// DeepSeek V3 MLA attention forward, MI355X (gfx950).
// B=2, S=2048, D=2048, H=16, NOPE=128, ROPE=64, VDIM=128, QKD=192.

typedef __bf16 bf16x8 __attribute__((ext_vector_type(8)));
typedef float floatx4 __attribute__((ext_vector_type(4)));
#define BF16 __hip_bfloat16

static __device__ __forceinline__ BF16 f2b(float x) { return __float2bfloat16(x); }

static __device__ __forceinline__ void load_lds16(const BF16* g, BF16* l) {
  __builtin_amdgcn_global_load_lds((__attribute__((address_space(1))) void*)(void*)g,
                                   (__attribute__((address_space(3))) void*)(void*)l,
                                   16, 0, 0);
}

// ---------------------------------------------------------------- multi-region cast f32->bf16
struct CastArgs {
  const float* src[6];
  BF16* dst[6];
  long n[6];
};
__global__ void cast_multi_k(CastArgs a) {
  int r = blockIdx.y;
  long n = a.n[r];
  const float* __restrict__ x = a.src[r];
  BF16* __restrict__ y = a.dst[r];
  for (long i = ((long)blockIdx.x * 256 + threadIdx.x) * 4; i + 3 < n;
       i += (long)gridDim.x * 1024) {
    float4 v = *(const float4*)(x + i);
    y[i+0] = f2b(v.x); y[i+1] = f2b(v.y); y[i+2] = f2b(v.z); y[i+3] = f2b(v.w);
  }
}

// ---------------------------------------------------------------- NT GEMM, m97-style LDS staging
// C[M][N] = A[M][K]*B[N][K]^T. 256 thr = 4 waves (2x2), 128x128 tile, BK=32.
// OUT_MODE: 0 = fp32 C;  2 = kv scatter -> Kt/Vt;  3 = q RoPE+scale scatter -> Qt.
template<int OUT_MODE>
__global__ __launch_bounds__(256) void gemm_lds(const BF16* __restrict__ A, const BF16* __restrict__ B,
                                                void* __restrict__ C, int M, int N, int K,
                                                const float* __restrict__ cosb,
                                                const float* __restrict__ sinb,
                                                BF16* __restrict__ P1, BF16* __restrict__ P2) {
  __shared__ __align__(16) BF16 As[128*32];
  __shared__ __align__(16) BF16 Bs[128*32];
  int tid = threadIdx.x, wave = tid >> 6, lane = tid & 63;
  int wr = wave >> 1, wc = wave & 1, lr = lane & 15, quad = lane >> 4;
  long m0 = (long)blockIdx.y * 128, n0 = (long)blockIdx.x * 128;

  int c0 = wave*64 + lane, c1 = c0 + 256;
  const BF16* ga0 = A + (m0 + (c0>>2))*(long)K + (c0&3)*8;
  const BF16* ga1 = A + (m0 + (c1>>2))*(long)K + (c1&3)*8;
  long bn0 = n0 + (c0>>2); if (bn0 >= N) bn0 = N-1;
  long bn1 = n0 + (c1>>2); if (bn1 >= N) bn1 = N-1;
  const BF16* gb0 = B + bn0*(long)K + (c0&3)*8;
  const BF16* gb1 = B + bn1*(long)K + (c1&3)*8;
  BF16* la0 = As + wave*512;
  BF16* la1 = As + wave*512 + 2048;
  BF16* lb0 = Bs + wave*512;
  BF16* lb1 = Bs + wave*512 + 2048;

  floatx4 acc[4][4] = {};
  for (int k0 = 0; k0 < K; k0 += 32) {
    __syncthreads();
    load_lds16(ga0 + k0, la0);
    load_lds16(ga1 + k0, la1);
    load_lds16(gb0 + k0, lb0);
    load_lds16(gb1 + k0, lb1);
    __syncthreads();
    bf16x8 a[4], b[4];
#pragma unroll
    for (int i = 0; i < 4; i++) a[i] = *(const bf16x8*)(As + (wr*64 + i*16 + lr)*32 + quad*8);
#pragma unroll
    for (int j = 0; j < 4; j++) b[j] = *(const bf16x8*)(Bs + (wc*64 + j*16 + lr)*32 + quad*8);
#pragma unroll
    for (int i = 0; i < 4; i++)
#pragma unroll
      for (int j = 0; j < 4; j++)
        acc[i][j] = __builtin_amdgcn_mfma_f32_16x16x32_bf16(a[i], b[j], acc[i][j], 0, 0, 0);
  }

  long n0w = n0 + wc*64;
  const float SCALE = 0.07216878364870322f; // 192^-0.5
#pragma unroll
  for (int i = 0; i < 4; i++) {
#pragma unroll
    for (int r = 0; r < 4; r++) {
      long row = m0 + wr*64 + i*16 + quad*4 + r;
      long b = row >> 11, s = row & 2047;
      if (OUT_MODE == 0) {
#pragma unroll
        for (int j = 0; j < 4; j++) {
          long col = n0w + j*16 + lr;
          if (col < N) ((float*)C)[row*(long)N + col] = acc[i][j][r];
        }
      } else if (OUT_MODE == 2) {
#pragma unroll
        for (int j = 0; j < 4; j++) {
          long col = n0w + j*16 + lr;
          long h = col >> 8, d = col & 255;
          long base = (b*16 + h)*2048 + s;
          if (d < 128) P1[base*192 + d] = f2b(acc[i][j][r]);
          else         P2[base*128 + d - 128] = f2b(acc[i][j][r]);
        }
      } else { // OUT_MODE == 3: q RoPE + SCALING -> Qt (B,H,S,192)
        bool rope = ((n0w % 192) == 128);
#pragma unroll
        for (int j = 0; j < 4; j++) {
          long col = n0w + j*16 + lr;
          float x = acc[i][j][r], val;
          if (rope) {
            int id = j*16 + lr;
            float partner = acc[i][j^2][r];
            float rot = (j < 2) ? -partner : partner;
            val = x*cosb[row*64 + id] + rot*sinb[row*64 + id];
          } else {
            val = x;
          }
          long h = col / 192, d = col % 192;
          P1[((b*16 + h)*2048 + s)*192 + d] = f2b(val * SCALE);
        }
      }
    }
  }
}

// ---------------------------------------------------------------- RMSNorm (row-wise), fp32 in, bf16 out
template<int D>
__global__ __launch_bounds__(256) void rmsnorm_k(const float* __restrict__ x, const float* __restrict__ w,
                                                 BF16* __restrict__ y, int ld_in, int ld_out) {
  long row = blockIdx.x;
  const float* xr = x + row * (long)ld_in;
  float ss = 0.f;
  for (int i = threadIdx.x * 4; i < D; i += 1024) {
    float4 v = *(const float4*)(xr + i);
    ss += v.x*v.x + v.y*v.y + v.z*v.z + v.w*v.w;
  }
#pragma unroll
  for (int off = 32; off > 0; off >>= 1) ss += __shfl_down(ss, off);
  __shared__ float red[4];
  if ((threadIdx.x & 63) == 0) red[threadIdx.x >> 6] = ss;
  __syncthreads();
  float tot = red[0] + red[1] + red[2] + red[3];
  float rs = rsqrtf(tot / (float)D + 1e-6f);
  BF16* yr = y + row * (long)ld_out;
  for (int i = threadIdx.x * 4; i < D; i += 1024) {
    float4 v = *(const float4*)(xr + i);
    yr[i+0] = f2b(v.x * w[i+0] * rs);
    yr[i+1] = f2b(v.y * w[i+1] * rs);
    yr[i+2] = f2b(v.z * w[i+2] * rs);
    yr[i+3] = f2b(v.w * w[i+3] * rs);
  }
}

// ---------------------------------------------------------------- RoPE on k_rot -> Kt[...,128:192] for all 16 heads
// krot points at qakv + 2048 (row stride ld).
__global__ void prep_krot_k(const float* __restrict__ krot, int ld, const float* __restrict__ cosb,
                            const float* __restrict__ sinb, BF16* __restrict__ Kt) {
  long row = blockIdx.x; int i = threadIdx.x;
  const float* kr = krot + row * (long)ld;
  float x = kr[i];
  float rot = (i < 32) ? -kr[i + 32] : kr[i - 32];
  BF16 v = f2b(x * cosb[row*64 + i] + rot * sinb[row*64 + i]);
  long b = row >> 11, s = row & 2047;
  long base = ((b*16)*2048 + s)*192 + 128 + i;
#pragma unroll
  for (int h = 0; h < 16; h++) Kt[base + (long)h*2048*192] = v;
}

// ---------------------------------------------------------------- causal flash attention
// flat grid 512; F&31 = (b,h) group (pins group to XCD F%8), F>>5 = q-tile pair idx.
// Block handles q-tiles {j, 31-j} (33 k-tiles, balanced). Q prescaled by 192^-0.5.
// Register-prefetch pipeline: tile kt+1's global loads issue before computing kt.
#define LK 200
#define LV 72
#define LP 72
__global__ __launch_bounds__(256) void flash_k(const BF16* __restrict__ Qt, const BF16* __restrict__ Kt,
                                               const BF16* __restrict__ Vt, BF16* __restrict__ O) {
  __shared__ __align__(16) BF16 Ks[64*LK];
  __shared__ __align__(16) BF16 Vs[128*LV];
  __shared__ __align__(16) BF16 Ps[4][16*LP];
  int tid = threadIdx.x, wave = tid >> 6, lane = tid & 63;
  int lr = lane & 15, quad = lane >> 4;
  int F = blockIdx.x;
  int g = F & 31, jidx = F >> 5;
  int h = g & 15, b = g >> 4;
  const BF16* Qb = Qt + ((long)(b*16 + h) * 2048) * 192;
  const BF16* Kb = Kt + ((long)(b*16 + h) * 2048) * 192;
  const BF16* Vb = Vt + ((long)(b*16 + h) * 2048) * 128;
  const float NEG_INF = -__builtin_inff();

  // staging geometry (fixed per thread)
  int krow[6], kcol[6];
#pragma unroll
  for (int i = 0; i < 6; i++) {
    int c = tid + 256*i;
    krow[i] = c / 24; kcol[i] = (c % 24) * 8;
  }
  int vd0base = wave * 8; // vd0 = (wave + it*4)*8

  bf16x8 kreg[6], vreg[4];
  auto stage_load = [&](int k0) {
#pragma unroll
    for (int i = 0; i < 6; i++)
      kreg[i] = *(const bf16x8*)(Kb + (long)(k0 + krow[i])*192 + kcol[i]);
#pragma unroll
    for (int it = 0; it < 4; it++)
      vreg[it] = *(const bf16x8*)(Vb + (long)(k0 + lane)*128 + vd0base + it*32);
  };
  auto stage_store = [&]() {
#pragma unroll
    for (int i = 0; i < 6; i++)
      *(bf16x8*)(Ks + krow[i]*LK + kcol[i]) = kreg[i];
#pragma unroll
    for (int it = 0; it < 4; it++) {
      int vd0 = vd0base + it*32;
#pragma unroll
      for (int j = 0; j < 8; j++) Vs[(vd0+j)*LV + lane] = ((BF16*)&vreg[it])[j];
    }
  };

  for (int half = 0; half < 2; half++) {
    int qt = (half == 0) ? jidx : 31 - jidx;
    int q0 = qt * 64;
    bf16x8 qf[6];
    {
      const BF16* qp = Qb + (long)(q0 + wave*16 + lr) * 192 + quad*8;
#pragma unroll
      for (int f = 0; f < 6; f++) qf[f] = *(const bf16x8*)(qp + f*32);
    }
    float m_i[4], l_i[4];
#pragma unroll
    for (int r = 0; r < 4; r++) { m_i[r] = NEG_INF; l_i[r] = 0.f; }
    floatx4 o_acc[8] = {};
    int nk = qt + 1;
    stage_load(0);
    for (int kt = 0; kt < nk; kt++) {
      int k0 = kt * 64;
      __syncthreads();   // prev-iter LDS reads complete
      stage_store();
      __syncthreads();
      if (kt + 1 < nk) stage_load(k0 + 64);  // prefetch: overlaps with compute below
      floatx4 st[4];
#pragma unroll
      for (int t = 0; t < 4; t++) {
        floatx4 c = {};
#pragma unroll
        for (int f = 0; f < 6; f++) {
          bf16x8 kf = *(const bf16x8*)(Ks + (t*16+lr)*LK + f*32 + quad*8);
          c = __builtin_amdgcn_mfma_f32_16x16x32_bf16(qf[f], kf, c, 0, 0, 0);
        }
        st[t] = c;
      }
      int rowbase = q0 + wave*16 + quad*4;
      float mt[4];
#pragma unroll
      for (int r = 0; r < 4; r++) mt[r] = NEG_INF;
      if (kt == qt) { // diagonal tile: causal mask
#pragma unroll
        for (int t = 0; t < 4; t++) {
          int col = k0 + t*16 + lr;
#pragma unroll
          for (int r = 0; r < 4; r++) {
            float s = st[t][r];
            if (col > rowbase + r) s = NEG_INF;
            st[t][r] = s;
            mt[r] = fmaxf(mt[r], s);
          }
        }
      } else {
#pragma unroll
        for (int t = 0; t < 4; t++)
#pragma unroll
          for (int r = 0; r < 4; r++) mt[r] = fmaxf(mt[r], st[t][r]);
      }
#pragma unroll
      for (int off = 1; off < 16; off <<= 1)
#pragma unroll
        for (int r = 0; r < 4; r++) mt[r] = fmaxf(mt[r], __shfl_xor(mt[r], off));
      float alpha[4], rsum[4];
#pragma unroll
      for (int r = 0; r < 4; r++) {
        float mn = fmaxf(m_i[r], mt[r]);
        alpha[r] = __expf(m_i[r] - mn);
        m_i[r] = mn;
        rsum[r] = 0.f;
      }
#pragma unroll
      for (int t = 0; t < 4; t++)
#pragma unroll
        for (int r = 0; r < 4; r++) {
          float p = __expf(st[t][r] - m_i[r]);
          st[t][r] = p;
          rsum[r] += p;
        }
#pragma unroll
      for (int off = 1; off < 16; off <<= 1)
#pragma unroll
        for (int r = 0; r < 4; r++) rsum[r] += __shfl_xor(rsum[r], off);
#pragma unroll
      for (int r = 0; r < 4; r++) l_i[r] = l_i[r]*alpha[r] + rsum[r];
#pragma unroll
      for (int v = 0; v < 8; v++)
#pragma unroll
        for (int r = 0; r < 4; r++) o_acc[v][r] *= alpha[r];
      // P (C-layout) -> wave-private LDS -> A-layout (no barrier needed)
#pragma unroll
      for (int t = 0; t < 4; t++)
#pragma unroll
        for (int r = 0; r < 4; r++)
          Ps[wave][(quad*4 + r)*LP + t*16 + lr] = f2b(st[t][r]);
#pragma unroll
      for (int kc = 0; kc < 2; kc++) {
        bf16x8 pa = *(const bf16x8*)(&Ps[wave][lr*LP + kc*32 + quad*8]);
#pragma unroll
        for (int v = 0; v < 8; v++) {
          bf16x8 vf = *(const bf16x8*)(&Vs[(v*16+lr)*LV + kc*32 + quad*8]);
          o_acc[v] = __builtin_amdgcn_mfma_f32_16x16x32_bf16(pa, vf, o_acc[v], 0, 0, 0);
        }
      }
    }
    long rowb = q0 + wave*16 + quad*4;
#pragma unroll
    for (int v = 0; v < 8; v++)
#pragma unroll
      for (int r = 0; r < 4; r++) {
        long row = rowb + r;
        O[((long)b*2048 + row)*2048 + h*128 + v*16 + lr] = f2b(o_acc[v][r] / l_i[r]);
      }
  }
}

// ---------------------------------------------------------------- launch
extern "C" void kernel_launch(void* const* d_in, const int* in_sizes, int n_in,
                              void* d_out, int out_size, void* d_ws, size_t ws_size,
                              hipStream_t stream) {
  const float* hidden      = (const float*)d_in[0];
  const float* cosb        = (const float*)d_in[1];
  const float* sinb        = (const float*)d_in[2];
  const float* q_a_W       = (const float*)d_in[3];
  const float* q_a_norm_w  = (const float*)d_in[4];
  const float* q_b_W       = (const float*)d_in[5];
  const float* kv_a_W      = (const float*)d_in[6];
  const float* kv_a_norm_w = (const float*)d_in[7];
  const float* kv_b_W      = (const float*)d_in[8];
  const float* o_W         = (const float*)d_in[9];
  float* out = (float*)d_out;

  const int Mrows = 4096;

  char* ws = (char*)d_ws; size_t off = 0;
  auto alloc = [&](size_t bytes) -> void* {
    void* p = ws + off; off = (off + bytes + 255) & ~(size_t)255; return p;
  };
  BF16* hb    = (BF16*)alloc((size_t)4096*2048*2);
  BF16* Wqakv = (BF16*)alloc((size_t)2112*2048*2);   // rows 0..1536 = q_a_W, 1536..2112 = kv_a_W
  BF16* Wqb   = (BF16*)alloc((size_t)3072*1536*2);
  BF16* Wkvb  = (BF16*)alloc((size_t)4096*512*2);
  BF16* Wo    = (BF16*)alloc((size_t)2048*2048*2);
  float* qakv = (float*)alloc((size_t)4096*2112*4);  // cols 0..1536 = q_a out, 1536..2112 = ckv
  BF16* qan   = (BF16*)alloc((size_t)4096*1536*2);
  BF16* kvn   = (BF16*)alloc((size_t)4096*512*2);
  BF16* Qt    = (BF16*)alloc((size_t)2*16*2048*192*2);
  BF16* Kt    = (BF16*)alloc((size_t)2*16*2048*192*2);
  BF16* Vt    = (BF16*)alloc((size_t)2*16*2048*128*2);
  BF16* attn  = (BF16*)alloc((size_t)4096*2048*2);

  CastArgs ca;
  ca.src[0] = hidden;  ca.dst[0] = hb;                 ca.n[0] = (long)4096*2048;
  ca.src[1] = q_a_W;   ca.dst[1] = Wqakv;              ca.n[1] = (long)1536*2048;
  ca.src[2] = kv_a_W;  ca.dst[2] = Wqakv + (long)1536*2048; ca.n[2] = (long)576*2048;
  ca.src[3] = q_b_W;   ca.dst[3] = Wqb;                ca.n[3] = (long)3072*1536;
  ca.src[4] = kv_b_W;  ca.dst[4] = Wkvb;               ca.n[4] = (long)4096*512;
  ca.src[5] = o_W;     ca.dst[5] = Wo;                 ca.n[5] = (long)2048*2048;
  cast_multi_k<<<dim3(1024, 6), dim3(256), 0, stream>>>(ca);

  // [q_a | ckv] = hidden @ [q_a_W | kv_a_W].T  (4096 x 2112, K=2048), fp32
  gemm_lds<0><<<dim3(17, 32), dim3(256), 0, stream>>>(hb, Wqakv, qakv, Mrows, 2112, 2048,
                                                      nullptr, nullptr, nullptr, nullptr);
  rmsnorm_k<1536><<<dim3(4096), dim3(256), 0, stream>>>(qakv, q_a_norm_w, qan, 2112, 1536);
  rmsnorm_k<512><<<dim3(4096), dim3(256), 0, stream>>>(qakv + 1536, kv_a_norm_w, kvn, 2112, 512);
  prep_krot_k<<<dim3(4096), dim3(64), 0, stream>>>(qakv + 2048, 2112, cosb, sinb, Kt);

  // q = qan @ q_b_W.T (4096x3072, K=1536), fused RoPE+scale -> Qt
  gemm_lds<3><<<dim3(24, 32), dim3(256), 0, stream>>>(qan, Wqb, nullptr, Mrows, 3072, 1536,
                                                      cosb, sinb, Qt, nullptr);
  // kv = kvn @ kv_b_W.T (4096x4096, K=512), fused scatter -> Kt/Vt
  gemm_lds<2><<<dim3(32, 32), dim3(256), 0, stream>>>(kvn, Wkvb, nullptr, Mrows, 4096, 512,
                                                      nullptr, nullptr, Kt, Vt);

  flash_k<<<dim3(512), dim3(256), 0, stream>>>(Qt, Kt, Vt, attn);

  // out = attn @ o_W.T (4096x2048, K=2048), fp32 -> d_out
  gemm_lds<0><<<dim3(16, 32), dim3(256), 0, stream>>>(attn, Wo, out, Mrows, 2048, 2048,
                                                      nullptr, nullptr, nullptr, nullptr);
}